// Round 2
// baseline (1251.881 us; speedup 1.0000x reference)
//
#include <hip/hip_runtime.h>

#define HID 256

// ---------------- degree count ----------------
__global__ void k_deg(const int* __restrict__ src, const int* __restrict__ dst,
                      int* __restrict__ deg_out, int* __restrict__ deg_in, int ne) {
    int e = blockIdx.x * blockDim.x + threadIdx.x;
    if (e < ne) {
        atomicAdd(&deg_out[src[e]], 1);
        atomicAdd(&deg_in[dst[e]], 1);
    }
}

// ---------------- norm factors ----------------
__global__ void k_norm(const int* __restrict__ deg_out, const int* __restrict__ deg_in,
                       float* __restrict__ norm_out, float* __restrict__ norm_in, int n) {
    int i = blockIdx.x * blockDim.x + threadIdx.x;
    if (i < n) {
        float dro = deg_out[i] > 0 ? (float)deg_out[i] : 1.0f;
        float dri = deg_in[i]  > 0 ? (float)deg_in[i]  : 1.0f;
        norm_out[i] = 1.0f / sqrtf(dro);
        norm_in[i]  = 1.0f / sqrtf(dri);
    }
}

// ---------------- exclusive scan of deg_in -> row_ptr (+ cursor copy) ----------------
__global__ void k_scan(const int* __restrict__ deg, int* __restrict__ rp,
                       int* __restrict__ cur, int n) {
    __shared__ int sd[1024];
    int tid = threadIdx.x;
    int run = 0;
    for (int start = 0; start < n; start += 1024) {
        int i = start + tid;
        int v = (i < n) ? deg[i] : 0;
        sd[tid] = v;
        __syncthreads();
        for (int o = 1; o < 1024; o <<= 1) {
            int t = (tid >= o) ? sd[tid - o] : 0;
            __syncthreads();
            sd[tid] += t;
            __syncthreads();
        }
        int incl = sd[tid];
        if (i < n) {
            int e = run + incl - v;
            rp[i] = e;
            cur[i] = e;
        }
        run += sd[1023];
        __syncthreads();
    }
    if (tid == 0) rp[n] = run;
}

// ---------------- scatter edges into CSR slots ----------------
__global__ void k_scatter(const int* __restrict__ src, const int* __restrict__ dst,
                          int* __restrict__ cur, int* __restrict__ colx, int ne) {
    int e = blockIdx.x * blockDim.x + threadIdx.x;
    if (e < ne) {
        int pos = atomicAdd(&cur[dst[e]], 1);
        colx[pos] = src[e];
    }
}

// ---------------- per-type linear: h[row0+r,:] = (x[r,:]@W + b) * norm_out ----------------
template <int K>
__global__ __launch_bounds__(256) void k_linear(const float* __restrict__ x,
                                                const float* __restrict__ W,
                                                const float* __restrict__ b,
                                                const float* __restrict__ norm_out,
                                                float* __restrict__ h,
                                                int row0, int nrows) {
    __shared__ __align__(16) float xs[8 * K];
    int tid = threadIdx.x;
    int rbase = blockIdx.x * 8;
    if (rbase >= nrows) return;

    // cooperative float4 load of 8 rows of x into LDS
    const float4* xp4 = (const float4*)(x + (size_t)rbase * K);
    float4* xs4 = (float4*)xs;
    #pragma unroll
    for (int i = tid; i < 8 * K / 4; i += 256) xs4[i] = xp4[i];
    __syncthreads();

    int col = tid;
    float acc[8] = {0.f, 0.f, 0.f, 0.f, 0.f, 0.f, 0.f, 0.f};
    for (int k = 0; k < K; k += 4) {
        float w0 = W[(k + 0) * HID + col];
        float w1 = W[(k + 1) * HID + col];
        float w2 = W[(k + 2) * HID + col];
        float w3 = W[(k + 3) * HID + col];
        #pragma unroll
        for (int r = 0; r < 8; r++) {
            float4 xv = *(const float4*)&xs[r * K + k];
            acc[r] += xv.x * w0 + xv.y * w1 + xv.z * w2 + xv.w * w3;
        }
    }
    float bb = b[col];
    #pragma unroll
    for (int r = 0; r < 8; r++) {
        int row = rbase + r;
        h[(size_t)(row0 + row) * HID + col] = (acc[r] + bb) * norm_out[row0 + row];
    }
}

// ---------------- pull-style SpMM over CSR; 1 wave per dst node ----------------
// mode 0: hout = relu(acc*norm_in + bias) * norm_out   (layer-0 output, prescaled for layer 1)
// mode 1: hout = acc*norm_in                            (pre-GEMM agg for layer 1)
__global__ __launch_bounds__(256) void k_spmm(const float* __restrict__ hin,
                                              const int* __restrict__ rp,
                                              const int* __restrict__ colx,
                                              const float* __restrict__ norm_in,
                                              const float* __restrict__ norm_out,
                                              const float* __restrict__ bias,
                                              float* __restrict__ hout,
                                              int n, int mode) {
    int node = blockIdx.x * 4 + (threadIdx.x >> 6);
    if (node >= n) return;
    int lane = threadIdx.x & 63;
    int start = rp[node], end = rp[node + 1];
    float4 acc = make_float4(0.f, 0.f, 0.f, 0.f);
    for (int j = start; j < end; j++) {
        int s = colx[j];
        float4 v = *(const float4*)(hin + (size_t)s * HID + lane * 4);
        acc.x += v.x; acc.y += v.y; acc.z += v.z; acc.w += v.w;
    }
    float ni = norm_in[node];
    float4 o;
    if (mode == 0) {
        float no = norm_out[node];
        float4 bb = *(const float4*)(bias + lane * 4);
        o.x = fmaxf(acc.x * ni + bb.x, 0.f) * no;
        o.y = fmaxf(acc.y * ni + bb.y, 0.f) * no;
        o.z = fmaxf(acc.z * ni + bb.z, 0.f) * no;
        o.w = fmaxf(acc.w * ni + bb.w, 0.f) * no;
    } else {
        o.x = acc.x * ni; o.y = acc.y * ni; o.z = acc.z * ni; o.w = acc.w * ni;
    }
    *(float4*)(hout + (size_t)node * HID + lane * 4) = o;
}

// ---------------- final in-place GEMM: io[row,:] = relu(io[row,:]@W + b) ----------------
__global__ __launch_bounds__(256) void k_gemm_final(float* __restrict__ io,
                                                    const float* __restrict__ W,
                                                    const float* __restrict__ b,
                                                    int n) {
    __shared__ __align__(16) float as[8 * HID];
    int tid = threadIdx.x;
    int rbase = blockIdx.x * 8;
    if (rbase >= n) return;

    size_t base = (size_t)rbase * HID;
    const float4* ip = (const float4*)(io + base);
    float4* as4 = (float4*)as;
    #pragma unroll
    for (int i = tid; i < 8 * HID / 4; i += 256) as4[i] = ip[i];
    __syncthreads();

    int col = tid;
    float acc[8] = {0.f, 0.f, 0.f, 0.f, 0.f, 0.f, 0.f, 0.f};
    for (int k = 0; k < HID; k += 4) {
        float w0 = W[(k + 0) * HID + col];
        float w1 = W[(k + 1) * HID + col];
        float w2 = W[(k + 2) * HID + col];
        float w3 = W[(k + 3) * HID + col];
        #pragma unroll
        for (int r = 0; r < 8; r++) {
            float4 xv = *(const float4*)&as[r * HID + k];
            acc[r] += xv.x * w0 + xv.y * w1 + xv.z * w2 + xv.w * w3;
        }
    }
    float bb = b[col];
    #pragma unroll
    for (int r = 0; r < 8; r++) {
        io[base + (size_t)r * HID + col] = fmaxf(acc[r] + bb, 0.f);
    }
}

extern "C" void kernel_launch(void* const* d_in, const int* in_sizes, int n_in,
                              void* d_out, int out_size, void* d_ws, size_t ws_size,
                              hipStream_t stream) {
    const float* x0     = (const float*)d_in[0];
    const float* x1     = (const float*)d_in[1];
    const float* x2     = (const float*)d_in[2];
    const float* W_fc0  = (const float*)d_in[3];
    const float* b_fc0  = (const float*)d_in[4];
    const float* W_fc1  = (const float*)d_in[5];
    const float* b_fc1  = (const float*)d_in[6];
    const float* W_fc2  = (const float*)d_in[7];
    const float* b_fc2  = (const float*)d_in[8];
    const float* bias_l0 = (const float*)d_in[9];
    const float* W_l1   = (const float*)d_in[10];
    const float* b_l1   = (const float*)d_in[11];
    const int*   src    = (const int*)d_in[12];
    const int*   dst    = (const int*)d_in[13];

    int n0 = in_sizes[0] / 256;
    int n1 = in_sizes[1] / 128;
    int n2 = in_sizes[2] / 512;
    int N  = n0 + n1 + n2;
    int NE = in_sizes[12];

    // workspace layout (256B-aligned slices)
    char* w = (char*)d_ws;
    auto alloc = [&](size_t bytes) {
        char* p = w;
        w += (bytes + 255) & ~(size_t)255;
        return p;
    };
    int*   deg_out  = (int*)alloc((size_t)2 * N * sizeof(int)); // deg_out + deg_in contiguous
    int*   deg_in   = deg_out + N;
    float* norm_out = (float*)alloc((size_t)N * sizeof(float));
    float* norm_in  = (float*)alloc((size_t)N * sizeof(float));
    int*   row_ptr  = (int*)alloc((size_t)(N + 1) * sizeof(int));
    int*   cursor   = (int*)alloc((size_t)N * sizeof(int));
    int*   colx     = (int*)alloc((size_t)NE * sizeof(int));
    float* h1       = (float*)alloc((size_t)N * HID * sizeof(float));

    float* h0 = (float*)d_out; // stage h0 / agg1 in the output buffer

    // graph preprocessing
    hipMemsetAsync(deg_out, 0, (size_t)2 * N * sizeof(int), stream);
    k_deg<<<(NE + 255) / 256, 256, 0, stream>>>(src, dst, deg_out, deg_in, NE);
    k_norm<<<(N + 255) / 256, 256, 0, stream>>>(deg_out, deg_in, norm_out, norm_in, N);
    k_scan<<<1, 1024, 0, stream>>>(deg_in, row_ptr, cursor, N);
    k_scatter<<<(NE + 255) / 256, 256, 0, stream>>>(src, dst, cursor, colx, NE);

    // per-type linear projections, prescaled by norm_out
    k_linear<256><<<(n0 + 7) / 8, 256, 0, stream>>>(x0, W_fc0, b_fc0, norm_out, h0, 0, n0);
    k_linear<128><<<(n1 + 7) / 8, 256, 0, stream>>>(x1, W_fc1, b_fc1, norm_out, h0, n0, n1);
    k_linear<512><<<(n2 + 7) / 8, 256, 0, stream>>>(x2, W_fc2, b_fc2, norm_out, h0, n0 + n1, n2);

    // layer 0: agg + relu + prescale for layer 1
    k_spmm<<<(N + 3) / 4, 256, 0, stream>>>(h0, row_ptr, colx, norm_in, norm_out, bias_l0,
                                            h1, N, 0);
    // layer 1: agg (with norm_in) into d_out
    k_spmm<<<(N + 3) / 4, 256, 0, stream>>>(h1, row_ptr, colx, norm_in, norm_out, nullptr,
                                            h0, N, 1);
    // final in-place transform: relu(agg @ W_l1 + b_l1)
    k_gemm_final<<<(N + 7) / 8, 256, 0, stream>>>(h0, W_l1, b_l1, N);
}

// Round 5
// 1116.378 us; speedup vs baseline: 1.1214x; 1.1214x over previous
//
#include <hip/hip_runtime.h>

#define HID 256

// ---------------- degree count ----------------
__global__ void k_deg(const int* __restrict__ src, const int* __restrict__ dst,
                      int* __restrict__ deg_out, int* __restrict__ deg_in, int ne) {
    int e = blockIdx.x * blockDim.x + threadIdx.x;
    if (e < ne) {
        atomicAdd(&deg_out[src[e]], 1);
        atomicAdd(&deg_in[dst[e]], 1);
    }
}

// ---------------- norm factors ----------------
__global__ void k_norm(const int* __restrict__ deg_out, const int* __restrict__ deg_in,
                       float* __restrict__ norm_out, float* __restrict__ norm_in, int n) {
    int i = blockIdx.x * blockDim.x + threadIdx.x;
    if (i < n) {
        float dro = deg_out[i] > 0 ? (float)deg_out[i] : 1.0f;
        float dri = deg_in[i]  > 0 ? (float)deg_in[i]  : 1.0f;
        norm_out[i] = 1.0f / sqrtf(dro);
        norm_in[i]  = 1.0f / sqrtf(dri);
    }
}

// ---------------- hierarchical exclusive scan: deg_in -> row_ptr ----------------
__global__ void k_scan_local(const int* __restrict__ deg, int* __restrict__ rp,
                             int* __restrict__ bsum, int n) {
    __shared__ int sd[1024];
    int tid = threadIdx.x;
    int i = blockIdx.x * 1024 + tid;
    int v = (i < n) ? deg[i] : 0;
    sd[tid] = v;
    __syncthreads();
    for (int o = 1; o < 1024; o <<= 1) {
        int t = (tid >= o) ? sd[tid - o] : 0;
        __syncthreads();
        sd[tid] += t;
        __syncthreads();
    }
    if (i < n) rp[i] = sd[tid] - v;           // local exclusive
    if (tid == 1023) bsum[blockIdx.x] = sd[1023];
}

__global__ void k_scan_bsum(int* __restrict__ bsum, int nb) {
    if (threadIdx.x == 0 && blockIdx.x == 0) {
        int run = 0;
        for (int i = 0; i < nb; i++) { int v = bsum[i]; bsum[i] = run; run += v; }
        bsum[nb] = run;
    }
}

__global__ void k_scan_add(int* __restrict__ rp, int* __restrict__ cur,
                           const int* __restrict__ bsum, int n, int nb) {
    int i = blockIdx.x * 1024 + threadIdx.x;
    if (i < n) {
        int e = rp[i] + bsum[blockIdx.x];
        rp[i] = e;
        cur[i] = e;
    }
    if (i == 0) rp[n] = bsum[nb];
}

// ---------------- scatter edges into CSR slots ----------------
__global__ void k_scatter(const int* __restrict__ src, const int* __restrict__ dst,
                          int* __restrict__ cur, int* __restrict__ colx, int ne) {
    int e = blockIdx.x * blockDim.x + threadIdx.x;
    if (e < ne) {
        int pos = atomicAdd(&cur[dst[e]], 1);
        colx[pos] = src[e];
    }
}

// ---------------- register-tiled fp32 GEMM: C = epi(A[M,K] @ B[K,256]) ----------------
// tile 64 rows x 256 cols, 256 threads, each computes 8x8. BK=8.
// EPI 0: C[r] = (acc + bias[c]) * scale[row0+r]   (per-type linear, prescaled by norm_out)
// EPI 1: C[r] = relu(acc + bias[c])               (final layer; in-place safe: full col width)
template <int K, int EPI>
__global__ __launch_bounds__(256) void k_gemm(const float* __restrict__ A,
                                              const float* __restrict__ B,
                                              const float* __restrict__ bias,
                                              const float* __restrict__ scale,
                                              float* __restrict__ C,
                                              int M, int row0) {
    __shared__ __align__(16) float As[8][64];
    __shared__ __align__(16) float Bs[8][256];
    int t = threadIdx.x;
    int tx = t & 31;         // col group: n0 = tx*8
    int ty = t >> 5;         // row group: m0 = ty*8
    int rbase = blockIdx.x * 64;

    float acc[8][8];
    #pragma unroll
    for (int i = 0; i < 8; i++)
        #pragma unroll
        for (int j = 0; j < 8; j++) acc[i][j] = 0.f;

    for (int k0 = 0; k0 < K; k0 += 8) {
        // stage A tile (64 rows x 8 k), transposed into As[k][row]
        if (t < 128) {
            int row = t >> 1, seg = t & 1;
            int gr = rbase + row;
            if (gr >= M) gr = M - 1;                  // clamp: row stays in-bounds, store guarded
            float4 a = *(const float4*)(A + (size_t)gr * K + k0 + seg * 4);
            As[seg * 4 + 0][row] = a.x;
            As[seg * 4 + 1][row] = a.y;
            As[seg * 4 + 2][row] = a.z;
            As[seg * 4 + 3][row] = a.w;
        }
        // stage B tile (8 k x 256)
        #pragma unroll
        for (int u = 0; u < 2; u++) {
            int idx = t + u * 256;
            int k = idx >> 6, c4 = idx & 63;
            *(float4*)&Bs[k][c4 * 4] = *(const float4*)(B + (size_t)(k0 + k) * HID + c4 * 4);
        }
        __syncthreads();
        #pragma unroll
        for (int k = 0; k < 8; k++) {
            float4 a0 = *(const float4*)&As[k][ty * 8];
            float4 a1 = *(const float4*)&As[k][ty * 8 + 4];
            float4 b0 = *(const float4*)&Bs[k][tx * 8];
            float4 b1 = *(const float4*)&Bs[k][tx * 8 + 4];
            float am[8] = {a0.x, a0.y, a0.z, a0.w, a1.x, a1.y, a1.z, a1.w};
            float bn[8] = {b0.x, b0.y, b0.z, b0.w, b1.x, b1.y, b1.z, b1.w};
            #pragma unroll
            for (int i = 0; i < 8; i++)
                #pragma unroll
                for (int j = 0; j < 8; j++)
                    acc[i][j] += am[i] * bn[j];
        }
        __syncthreads();
    }

    // epilogue
    float4 bb0 = *(const float4*)(bias + tx * 8);
    float4 bb1 = *(const float4*)(bias + tx * 8 + 4);
    float bc[8] = {bb0.x, bb0.y, bb0.z, bb0.w, bb1.x, bb1.y, bb1.z, bb1.w};
    #pragma unroll
    for (int i = 0; i < 8; i++) {
        int lr = ty * 8 + i;
        int gr = rbase + lr;
        if (gr >= M) break;
        float s = (EPI == 0) ? scale[row0 + gr] : 1.f;
        float4 o0, o1;
        if (EPI == 0) {
            o0.x = (acc[i][0] + bc[0]) * s; o0.y = (acc[i][1] + bc[1]) * s;
            o0.z = (acc[i][2] + bc[2]) * s; o0.w = (acc[i][3] + bc[3]) * s;
            o1.x = (acc[i][4] + bc[4]) * s; o1.y = (acc[i][5] + bc[5]) * s;
            o1.z = (acc[i][6] + bc[6]) * s; o1.w = (acc[i][7] + bc[7]) * s;
        } else {
            o0.x = fmaxf(acc[i][0] + bc[0], 0.f); o0.y = fmaxf(acc[i][1] + bc[1], 0.f);
            o0.z = fmaxf(acc[i][2] + bc[2], 0.f); o0.w = fmaxf(acc[i][3] + bc[3], 0.f);
            o1.x = fmaxf(acc[i][4] + bc[4], 0.f); o1.y = fmaxf(acc[i][5] + bc[5], 0.f);
            o1.z = fmaxf(acc[i][6] + bc[6], 0.f); o1.w = fmaxf(acc[i][7] + bc[7], 0.f);
        }
        float* cp = C + (size_t)(row0 + gr) * HID + tx * 8;
        *(float4*)cp = o0;
        *(float4*)(cp + 4) = o1;
    }
}

// ---------------- pull-style SpMM over CSR; 1 wave per dst node; 8x unrolled ----------------
// mode 0: hout = relu(acc*norm_in + bias) * norm_out   (layer-0 out, prescaled for layer 1)
// mode 1: hout = acc*norm_in                            (pre-GEMM agg for layer 1)
__global__ __launch_bounds__(256) void k_spmm(const float* __restrict__ hin,
                                              const int* __restrict__ rp,
                                              const int* __restrict__ colx,
                                              const float* __restrict__ norm_in,
                                              const float* __restrict__ norm_out,
                                              const float* __restrict__ bias,
                                              float* __restrict__ hout,
                                              int n, int mode) {
    int node = blockIdx.x * 4 + (threadIdx.x >> 6);
    if (node >= n) return;
    int lane = threadIdx.x & 63;
    int start = rp[node], end = rp[node + 1];
    const float* hb = hin + lane * 4;

    float4 acc = make_float4(0.f, 0.f, 0.f, 0.f);
    float4 acc2 = make_float4(0.f, 0.f, 0.f, 0.f);
    int j = start;
    for (; j + 8 <= end; j += 8) {
        int s0 = colx[j + 0], s1 = colx[j + 1], s2 = colx[j + 2], s3 = colx[j + 3];
        int s4 = colx[j + 4], s5 = colx[j + 5], s6 = colx[j + 6], s7 = colx[j + 7];
        float4 v0 = *(const float4*)(hb + (size_t)s0 * HID);
        float4 v1 = *(const float4*)(hb + (size_t)s1 * HID);
        float4 v2 = *(const float4*)(hb + (size_t)s2 * HID);
        float4 v3 = *(const float4*)(hb + (size_t)s3 * HID);
        float4 v4 = *(const float4*)(hb + (size_t)s4 * HID);
        float4 v5 = *(const float4*)(hb + (size_t)s5 * HID);
        float4 v6 = *(const float4*)(hb + (size_t)s6 * HID);
        float4 v7 = *(const float4*)(hb + (size_t)s7 * HID);
        acc.x += v0.x + v1.x; acc.y += v0.y + v1.y; acc.z += v0.z + v1.z; acc.w += v0.w + v1.w;
        acc2.x += v2.x + v3.x; acc2.y += v2.y + v3.y; acc2.z += v2.z + v3.z; acc2.w += v2.w + v3.w;
        acc.x += v4.x + v5.x; acc.y += v4.y + v5.y; acc.z += v4.z + v5.z; acc.w += v4.w + v5.w;
        acc2.x += v6.x + v7.x; acc2.y += v6.y + v7.y; acc2.z += v6.z + v7.z; acc2.w += v6.w + v7.w;
    }
    for (; j < end; j++) {
        int s = colx[j];
        float4 v = *(const float4*)(hb + (size_t)s * HID);
        acc.x += v.x; acc.y += v.y; acc.z += v.z; acc.w += v.w;
    }
    acc.x += acc2.x; acc.y += acc2.y; acc.z += acc2.z; acc.w += acc2.w;

    float ni = norm_in[node];
    float4 o;
    if (mode == 0) {
        float no = norm_out[node];
        float4 bb = *(const float4*)(bias + lane * 4);
        o.x = fmaxf(acc.x * ni + bb.x, 0.f) * no;
        o.y = fmaxf(acc.y * ni + bb.y, 0.f) * no;
        o.z = fmaxf(acc.z * ni + bb.z, 0.f) * no;
        o.w = fmaxf(acc.w * ni + bb.w, 0.f) * no;
    } else {
        o.x = acc.x * ni; o.y = acc.y * ni; o.z = acc.z * ni; o.w = acc.w * ni;
    }
    *(float4*)(hout + (size_t)node * HID + lane * 4) = o;
}

extern "C" void kernel_launch(void* const* d_in, const int* in_sizes, int n_in,
                              void* d_out, int out_size, void* d_ws, size_t ws_size,
                              hipStream_t stream) {
    const float* x0      = (const float*)d_in[0];
    const float* x1      = (const float*)d_in[1];
    const float* x2      = (const float*)d_in[2];
    const float* W_fc0   = (const float*)d_in[3];
    const float* b_fc0   = (const float*)d_in[4];
    const float* W_fc1   = (const float*)d_in[5];
    const float* b_fc1   = (const float*)d_in[6];
    const float* W_fc2   = (const float*)d_in[7];
    const float* b_fc2   = (const float*)d_in[8];
    const float* bias_l0 = (const float*)d_in[9];
    const float* W_l1    = (const float*)d_in[10];
    const float* b_l1    = (const float*)d_in[11];
    const int*   src     = (const int*)d_in[12];
    const int*   dst     = (const int*)d_in[13];

    int n0 = in_sizes[0] / 256;
    int n1 = in_sizes[1] / 128;
    int n2 = in_sizes[2] / 512;
    int N  = n0 + n1 + n2;
    int NE = in_sizes[12];
    int nscan = (N + 1023) / 1024;

    // workspace layout (256B-aligned slices)
    char* w = (char*)d_ws;
    auto alloc = [&](size_t bytes) {
        char* p = w;
        w += (bytes + 255) & ~(size_t)255;
        return p;
    };
    int*   deg_out  = (int*)alloc((size_t)2 * N * sizeof(int)); // deg_out + deg_in contiguous
    int*   deg_in   = deg_out + N;
    float* norm_out = (float*)alloc((size_t)N * sizeof(float));
    float* norm_in  = (float*)alloc((size_t)N * sizeof(float));
    int*   row_ptr  = (int*)alloc((size_t)(N + 1) * sizeof(int));
    int*   cursor   = (int*)alloc((size_t)N * sizeof(int));
    int*   bsum     = (int*)alloc((size_t)(nscan + 1) * sizeof(int));
    int*   colx     = (int*)alloc((size_t)NE * sizeof(int));
    float* h1       = (float*)alloc((size_t)N * HID * sizeof(float));

    float* h0 = (float*)d_out; // stage h0 / agg1 in the output buffer

    // graph preprocessing
    hipMemsetAsync(deg_out, 0, (size_t)2 * N * sizeof(int), stream);
    k_deg<<<(NE + 255) / 256, 256, 0, stream>>>(src, dst, deg_out, deg_in, NE);
    k_norm<<<(N + 255) / 256, 256, 0, stream>>>(deg_out, deg_in, norm_out, norm_in, N);
    k_scan_local<<<nscan, 1024, 0, stream>>>(deg_in, row_ptr, bsum, N);
    k_scan_bsum<<<1, 64, 0, stream>>>(bsum, nscan);
    k_scan_add<<<nscan, 1024, 0, stream>>>(row_ptr, cursor, bsum, N, nscan);
    k_scatter<<<(NE + 255) / 256, 256, 0, stream>>>(src, dst, cursor, colx, NE);

    // per-type linear projections, prescaled by norm_out (register-tiled GEMM)
    k_gemm<256, 0><<<(n0 + 63) / 64, 256, 0, stream>>>(x0, W_fc0, b_fc0, norm_out, h0, n0, 0);
    k_gemm<128, 0><<<(n1 + 63) / 64, 256, 0, stream>>>(x1, W_fc1, b_fc1, norm_out, h0, n1, n0);
    k_gemm<512, 0><<<(n2 + 63) / 64, 256, 0, stream>>>(x2, W_fc2, b_fc2, norm_out, h0, n2, n0 + n1);

    // layer 0: agg + relu + prescale for layer 1
    k_spmm<<<(N + 3) / 4, 256, 0, stream>>>(h0, row_ptr, colx, norm_in, norm_out, bias_l0,
                                            h1, N, 0);
    // layer 1: agg (with norm_in) into d_out
    k_spmm<<<(N + 3) / 4, 256, 0, stream>>>(h1, row_ptr, colx, norm_in, norm_out, nullptr,
                                            h0, N, 1);
    // final in-place transform: relu(agg @ W_l1 + b_l1)
    k_gemm<256, 1><<<(N + 63) / 64, 256, 0, stream>>>(h0, W_l1, b_l1, nullptr, h0, N, 0);
}

// Round 7
// 877.047 us; speedup vs baseline: 1.4274x; 1.2729x over previous
//
#include <hip/hip_runtime.h>
#include <hip/hip_fp16.h>

#define HID 256

// ---------- fp16 pack/unpack helpers ----------
__device__ inline unsigned int h2_as_u32(__half2 h) {
    union { __half2 h; unsigned int u; } c; c.h = h; return c.u;
}
__device__ inline float4 u2_to_f4(uint2 u) {
    union { unsigned int u; __half2 h; } a, b;
    a.u = u.x; b.u = u.y;
    float2 fa = __half22float2(a.h);
    float2 fb = __half22float2(b.h);
    return make_float4(fa.x, fa.y, fb.x, fb.y);
}

// ---------------- degree count ----------------
__global__ void k_deg(const int* __restrict__ src, const int* __restrict__ dst,
                      int* __restrict__ deg_out, int* __restrict__ deg_in, int ne) {
    int e = blockIdx.x * blockDim.x + threadIdx.x;
    if (e < ne) {
        atomicAdd(&deg_out[src[e]], 1);
        atomicAdd(&deg_in[dst[e]], 1);
    }
}

// ---------------- norm factors ----------------
__global__ void k_norm(const int* __restrict__ deg_out, const int* __restrict__ deg_in,
                       float* __restrict__ norm_out, float* __restrict__ norm_in, int n) {
    int i = blockIdx.x * blockDim.x + threadIdx.x;
    if (i < n) {
        float dro = deg_out[i] > 0 ? (float)deg_out[i] : 1.0f;
        float dri = deg_in[i]  > 0 ? (float)deg_in[i]  : 1.0f;
        norm_out[i] = 1.0f / sqrtf(dro);
        norm_in[i]  = 1.0f / sqrtf(dri);
    }
}

// ---------------- hierarchical exclusive scan: deg_in -> row_ptr ----------------
__global__ void k_scan_local(const int* __restrict__ deg, int* __restrict__ rp,
                             int* __restrict__ bsum, int n) {
    __shared__ int sd[1024];
    int tid = threadIdx.x;
    int i = blockIdx.x * 1024 + tid;
    int v = (i < n) ? deg[i] : 0;
    sd[tid] = v;
    __syncthreads();
    for (int o = 1; o < 1024; o <<= 1) {
        int t = (tid >= o) ? sd[tid - o] : 0;
        __syncthreads();
        sd[tid] += t;
        __syncthreads();
    }
    if (i < n) rp[i] = sd[tid] - v;           // local exclusive
    if (tid == 1023) bsum[blockIdx.x] = sd[1023];
}

__global__ void k_scan_bsum(int* __restrict__ bsum, int nb) {
    if (threadIdx.x == 0 && blockIdx.x == 0) {
        int run = 0;
        for (int i = 0; i < nb; i++) { int v = bsum[i]; bsum[i] = run; run += v; }
        bsum[nb] = run;
    }
}

__global__ void k_scan_add(int* __restrict__ rp, int* __restrict__ cur,
                           const int* __restrict__ bsum, int n, int nb) {
    int i = blockIdx.x * 1024 + threadIdx.x;
    if (i < n) {
        int e = rp[i] + bsum[blockIdx.x];
        rp[i] = e;
        cur[i] = e;
    }
    if (i == 0) rp[n] = bsum[nb];
}

// ---------------- scatter edges into CSR slots ----------------
__global__ void k_scatter(const int* __restrict__ src, const int* __restrict__ dst,
                          int* __restrict__ cur, int* __restrict__ colx, int ne) {
    int e = blockIdx.x * blockDim.x + threadIdx.x;
    if (e < ne) {
        int pos = atomicAdd(&cur[dst[e]], 1);
        colx[pos] = src[e];
    }
}

// ---------------- register-tiled fp32 GEMM: C = epi(A[M,K] @ B[K,256]) ----------------
// tile 64 rows x 256 cols, 256 threads, each computes 8x8. BK=8.
// EPI 0: C(fp16)[r] = (acc + bias[c]) * scale[row0+r]  (per-type linear, prescaled by norm_out)
// EPI 1: C(fp32)[r] = relu(acc + bias[c])              (final layer; in-place safe: full col width)
template <int K, int EPI>
__global__ __launch_bounds__(256) void k_gemm(const float* __restrict__ A,
                                              const float* __restrict__ B,
                                              const float* __restrict__ bias,
                                              const float* __restrict__ scale,
                                              void* __restrict__ Cv,
                                              int M, int row0) {
    __shared__ __align__(16) float As[8][64];
    __shared__ __align__(16) float Bs[8][256];
    int t = threadIdx.x;
    int tx = t & 31;         // col group: n0 = tx*8
    int ty = t >> 5;         // row group: m0 = ty*8
    int rbase = blockIdx.x * 64;

    float acc[8][8];
    #pragma unroll
    for (int i = 0; i < 8; i++)
        #pragma unroll
        for (int j = 0; j < 8; j++) acc[i][j] = 0.f;

    for (int k0 = 0; k0 < K; k0 += 8) {
        // stage A tile (64 rows x 8 k), transposed into As[k][row]
        if (t < 128) {
            int row = t >> 1, seg = t & 1;
            int gr = rbase + row;
            if (gr >= M) gr = M - 1;                  // clamp: row stays in-bounds, store guarded
            float4 a = *(const float4*)(A + (size_t)gr * K + k0 + seg * 4);
            As[seg * 4 + 0][row] = a.x;
            As[seg * 4 + 1][row] = a.y;
            As[seg * 4 + 2][row] = a.z;
            As[seg * 4 + 3][row] = a.w;
        }
        // stage B tile (8 k x 256)
        #pragma unroll
        for (int u = 0; u < 2; u++) {
            int idx = t + u * 256;
            int k = idx >> 6, c4 = idx & 63;
            *(float4*)&Bs[k][c4 * 4] = *(const float4*)(B + (size_t)(k0 + k) * HID + c4 * 4);
        }
        __syncthreads();
        #pragma unroll
        for (int k = 0; k < 8; k++) {
            float4 a0 = *(const float4*)&As[k][ty * 8];
            float4 a1 = *(const float4*)&As[k][ty * 8 + 4];
            float4 b0 = *(const float4*)&Bs[k][tx * 8];
            float4 b1 = *(const float4*)&Bs[k][tx * 8 + 4];
            float am[8] = {a0.x, a0.y, a0.z, a0.w, a1.x, a1.y, a1.z, a1.w};
            float bn[8] = {b0.x, b0.y, b0.z, b0.w, b1.x, b1.y, b1.z, b1.w};
            #pragma unroll
            for (int i = 0; i < 8; i++)
                #pragma unroll
                for (int j = 0; j < 8; j++)
                    acc[i][j] += am[i] * bn[j];
        }
        __syncthreads();
    }

    // epilogue
    float4 bb0 = *(const float4*)(bias + tx * 8);
    float4 bb1 = *(const float4*)(bias + tx * 8 + 4);
    float bc[8] = {bb0.x, bb0.y, bb0.z, bb0.w, bb1.x, bb1.y, bb1.z, bb1.w};
    #pragma unroll
    for (int i = 0; i < 8; i++) {
        int lr = ty * 8 + i;
        int gr = rbase + lr;
        if (gr >= M) break;
        float e[8];
        if (EPI == 0) {
            float s = scale[row0 + gr];
            #pragma unroll
            for (int j = 0; j < 8; j++) e[j] = (acc[i][j] + bc[j]) * s;
            // pack 8 floats -> 8 halves (16B store)
            uint4 st;
            st.x = h2_as_u32(__floats2half2_rn(e[0], e[1]));
            st.y = h2_as_u32(__floats2half2_rn(e[2], e[3]));
            st.z = h2_as_u32(__floats2half2_rn(e[4], e[5]));
            st.w = h2_as_u32(__floats2half2_rn(e[6], e[7]));
            __half* C = (__half*)Cv;
            *(uint4*)(C + (size_t)(row0 + gr) * HID + tx * 8) = st;
        } else {
            #pragma unroll
            for (int j = 0; j < 8; j++) e[j] = fmaxf(acc[i][j] + bc[j], 0.f);
            float* C = (float*)Cv;
            float* cp = C + (size_t)(row0 + gr) * HID + tx * 8;
            *(float4*)cp = make_float4(e[0], e[1], e[2], e[3]);
            *(float4*)(cp + 4) = make_float4(e[4], e[5], e[6], e[7]);
        }
    }
}

// ---------------- pull-style SpMM over CSR (fp16 rows); 1 wave per dst node; 8x unrolled ----
// MODE 0: hout(fp16) = relu(acc*norm_in + bias) * norm_out  (layer-0 out, prescaled for layer 1)
// MODE 1: hout(fp32) = acc*norm_in                           (pre-GEMM agg for layer 1)
template <int MODE>
__global__ __launch_bounds__(256) void k_spmm(const __half* __restrict__ hin,
                                              const int* __restrict__ rp,
                                              const int* __restrict__ colx,
                                              const float* __restrict__ norm_in,
                                              const float* __restrict__ norm_out,
                                              const float* __restrict__ bias,
                                              void* __restrict__ hout,
                                              int n) {
    int node = blockIdx.x * 4 + (threadIdx.x >> 6);
    if (node >= n) return;
    int lane = threadIdx.x & 63;
    int start = rp[node], end = rp[node + 1];
    const __half* hb = hin + lane * 4;   // each lane covers feature cols [lane*4, lane*4+4)

    float4 acc = make_float4(0.f, 0.f, 0.f, 0.f);
    float4 acc2 = make_float4(0.f, 0.f, 0.f, 0.f);
    int j = start;
    for (; j + 8 <= end; j += 8) {
        int s0 = colx[j + 0], s1 = colx[j + 1], s2 = colx[j + 2], s3 = colx[j + 3];
        int s4 = colx[j + 4], s5 = colx[j + 5], s6 = colx[j + 6], s7 = colx[j + 7];
        uint2 u0 = *(const uint2*)(hb + (size_t)s0 * HID);
        uint2 u1 = *(const uint2*)(hb + (size_t)s1 * HID);
        uint2 u2 = *(const uint2*)(hb + (size_t)s2 * HID);
        uint2 u3 = *(const uint2*)(hb + (size_t)s3 * HID);
        uint2 u4 = *(const uint2*)(hb + (size_t)s4 * HID);
        uint2 u5 = *(const uint2*)(hb + (size_t)s5 * HID);
        uint2 u6 = *(const uint2*)(hb + (size_t)s6 * HID);
        uint2 u7 = *(const uint2*)(hb + (size_t)s7 * HID);
        float4 v0 = u2_to_f4(u0), v1 = u2_to_f4(u1), v2 = u2_to_f4(u2), v3 = u2_to_f4(u3);
        float4 v4 = u2_to_f4(u4), v5 = u2_to_f4(u5), v6 = u2_to_f4(u6), v7 = u2_to_f4(u7);
        acc.x += v0.x + v1.x; acc.y += v0.y + v1.y; acc.z += v0.z + v1.z; acc.w += v0.w + v1.w;
        acc2.x += v2.x + v3.x; acc2.y += v2.y + v3.y; acc2.z += v2.z + v3.z; acc2.w += v2.w + v3.w;
        acc.x += v4.x + v5.x; acc.y += v4.y + v5.y; acc.z += v4.z + v5.z; acc.w += v4.w + v5.w;
        acc2.x += v6.x + v7.x; acc2.y += v6.y + v7.y; acc2.z += v6.z + v7.z; acc2.w += v6.w + v7.w;
    }
    for (; j < end; j++) {
        int s = colx[j];
        float4 v = u2_to_f4(*(const uint2*)(hb + (size_t)s * HID));
        acc.x += v.x; acc.y += v.y; acc.z += v.z; acc.w += v.w;
    }
    acc.x += acc2.x; acc.y += acc2.y; acc.z += acc2.z; acc.w += acc2.w;

    float ni = norm_in[node];
    if (MODE == 0) {
        float no = norm_out[node];
        float4 bb = *(const float4*)(bias + lane * 4);
        float o0 = fmaxf(acc.x * ni + bb.x, 0.f) * no;
        float o1 = fmaxf(acc.y * ni + bb.y, 0.f) * no;
        float o2 = fmaxf(acc.z * ni + bb.z, 0.f) * no;
        float o3 = fmaxf(acc.w * ni + bb.w, 0.f) * no;
        uint2 st;
        st.x = h2_as_u32(__floats2half2_rn(o0, o1));
        st.y = h2_as_u32(__floats2half2_rn(o2, o3));
        *(uint2*)((__half*)hout + (size_t)node * HID + lane * 4) = st;
    } else {
        float4 o = make_float4(acc.x * ni, acc.y * ni, acc.z * ni, acc.w * ni);
        *(float4*)((float*)hout + (size_t)node * HID + lane * 4) = o;
    }
}

extern "C" void kernel_launch(void* const* d_in, const int* in_sizes, int n_in,
                              void* d_out, int out_size, void* d_ws, size_t ws_size,
                              hipStream_t stream) {
    const float* x0      = (const float*)d_in[0];
    const float* x1      = (const float*)d_in[1];
    const float* x2      = (const float*)d_in[2];
    const float* W_fc0   = (const float*)d_in[3];
    const float* b_fc0   = (const float*)d_in[4];
    const float* W_fc1   = (const float*)d_in[5];
    const float* b_fc1   = (const float*)d_in[6];
    const float* W_fc2   = (const float*)d_in[7];
    const float* b_fc2   = (const float*)d_in[8];
    const float* bias_l0 = (const float*)d_in[9];
    const float* W_l1    = (const float*)d_in[10];
    const float* b_l1    = (const float*)d_in[11];
    const int*   src     = (const int*)d_in[12];
    const int*   dst     = (const int*)d_in[13];

    int n0 = in_sizes[0] / 256;
    int n1 = in_sizes[1] / 128;
    int n2 = in_sizes[2] / 512;
    int N  = n0 + n1 + n2;
    int NE = in_sizes[12];
    int nscan = (N + 1023) / 1024;

    // workspace layout (256B-aligned slices)
    char* w = (char*)d_ws;
    auto alloc = [&](size_t bytes) {
        char* p = w;
        w += (bytes + 255) & ~(size_t)255;
        return p;
    };
    int*    deg_out  = (int*)alloc((size_t)2 * N * sizeof(int)); // deg_out + deg_in contiguous
    int*    deg_in   = deg_out + N;
    float*  norm_out = (float*)alloc((size_t)N * sizeof(float));
    float*  norm_in  = (float*)alloc((size_t)N * sizeof(float));
    int*    row_ptr  = (int*)alloc((size_t)(N + 1) * sizeof(int));
    int*    cursor   = (int*)alloc((size_t)N * sizeof(int));
    int*    bsum     = (int*)alloc((size_t)(nscan + 1) * sizeof(int));
    int*    colx     = (int*)alloc((size_t)NE * sizeof(int));
    __half* h0h      = (__half*)alloc((size_t)N * HID * sizeof(__half));
    __half* h1h      = (__half*)alloc((size_t)N * HID * sizeof(__half));

    float* aggf = (float*)d_out; // layer-1 agg (fp32) staged in the output buffer

    // graph preprocessing
    hipMemsetAsync(deg_out, 0, (size_t)2 * N * sizeof(int), stream);
    k_deg<<<(NE + 255) / 256, 256, 0, stream>>>(src, dst, deg_out, deg_in, NE);
    k_norm<<<(N + 255) / 256, 256, 0, stream>>>(deg_out, deg_in, norm_out, norm_in, N);
    k_scan_local<<<nscan, 1024, 0, stream>>>(deg_in, row_ptr, bsum, N);
    k_scan_bsum<<<1, 64, 0, stream>>>(bsum, nscan);
    k_scan_add<<<nscan, 1024, 0, stream>>>(row_ptr, cursor, bsum, N, nscan);
    k_scatter<<<(NE + 255) / 256, 256, 0, stream>>>(src, dst, cursor, colx, NE);

    // per-type linear projections -> fp16 h0, prescaled by norm_out
    k_gemm<256, 0><<<(n0 + 63) / 64, 256, 0, stream>>>(x0, W_fc0, b_fc0, norm_out, h0h, n0, 0);
    k_gemm<128, 0><<<(n1 + 63) / 64, 256, 0, stream>>>(x1, W_fc1, b_fc1, norm_out, h0h, n1, n0);
    k_gemm<512, 0><<<(n2 + 63) / 64, 256, 0, stream>>>(x2, W_fc2, b_fc2, norm_out, h0h, n2, n0 + n1);

    // layer 0: agg + relu + prescale for layer 1 -> fp16 h1
    k_spmm<0><<<(N + 3) / 4, 256, 0, stream>>>(h0h, row_ptr, colx, norm_in, norm_out, bias_l0,
                                               h1h, N);
    // layer 1: agg (with norm_in) -> fp32 in d_out
    k_spmm<1><<<(N + 3) / 4, 256, 0, stream>>>(h1h, row_ptr, colx, norm_in, norm_out, nullptr,
                                               aggf, N);
    // final in-place transform: relu(agg @ W_l1 + b_l1)
    k_gemm<256, 1><<<(N + 63) / 64, 256, 0, stream>>>(aggf, W_l1, b_l1, nullptr, d_out, N, 0);
}

// Round 8
// 672.510 us; speedup vs baseline: 1.8615x; 1.3041x over previous
//
#include <hip/hip_runtime.h>
#include <hip/hip_fp16.h>

#define HID 256

typedef _Float16 f16x8 __attribute__((ext_vector_type(8)));
typedef float    f32x4 __attribute__((ext_vector_type(4)));

// ---------- fp16 pack/unpack helpers ----------
__device__ inline unsigned int h2_as_u32(__half2 h) {
    union { __half2 h; unsigned int u; } c; c.h = h; return c.u;
}
__device__ inline float4 u2_to_f4(uint2 u) {
    union { unsigned int u; __half2 h; } a, b;
    a.u = u.x; b.u = u.y;
    float2 fa = __half22float2(a.h);
    float2 fb = __half22float2(b.h);
    return make_float4(fa.x, fa.y, fb.x, fb.y);
}

// ---------------- degree count ----------------
__global__ void k_deg(const int* __restrict__ src, const int* __restrict__ dst,
                      int* __restrict__ deg_out, int* __restrict__ deg_in, int ne) {
    int e = blockIdx.x * blockDim.x + threadIdx.x;
    if (e < ne) {
        atomicAdd(&deg_out[src[e]], 1);
        atomicAdd(&deg_in[dst[e]], 1);
    }
}

// ---------------- norm factors ----------------
__global__ void k_norm(const int* __restrict__ deg_out, const int* __restrict__ deg_in,
                       float* __restrict__ norm_out, float* __restrict__ norm_in, int n) {
    int i = blockIdx.x * blockDim.x + threadIdx.x;
    if (i < n) {
        float dro = deg_out[i] > 0 ? (float)deg_out[i] : 1.0f;
        float dri = deg_in[i]  > 0 ? (float)deg_in[i]  : 1.0f;
        norm_out[i] = 1.0f / sqrtf(dro);
        norm_in[i]  = 1.0f / sqrtf(dri);
    }
}

// ---------------- hierarchical exclusive scan: deg_in -> row_ptr ----------------
__global__ void k_scan_local(const int* __restrict__ deg, int* __restrict__ rp,
                             int* __restrict__ bsum, int n) {
    __shared__ int sd[1024];
    int tid = threadIdx.x;
    int i = blockIdx.x * 1024 + tid;
    int v = (i < n) ? deg[i] : 0;
    sd[tid] = v;
    __syncthreads();
    for (int o = 1; o < 1024; o <<= 1) {
        int t = (tid >= o) ? sd[tid - o] : 0;
        __syncthreads();
        sd[tid] += t;
        __syncthreads();
    }
    if (i < n) rp[i] = sd[tid] - v;           // local exclusive
    if (tid == 1023) bsum[blockIdx.x] = sd[1023];
}

__global__ void k_scan_bsum(int* __restrict__ bsum, int nb) {
    if (threadIdx.x == 0 && blockIdx.x == 0) {
        int run = 0;
        for (int i = 0; i < nb; i++) { int v = bsum[i]; bsum[i] = run; run += v; }
        bsum[nb] = run;
    }
}

__global__ void k_scan_add(int* __restrict__ rp, int* __restrict__ cur,
                           const int* __restrict__ bsum, int n, int nb) {
    int i = blockIdx.x * 1024 + threadIdx.x;
    if (i < n) {
        int e = rp[i] + bsum[blockIdx.x];
        rp[i] = e;
        cur[i] = e;
    }
    if (i == 0) rp[n] = bsum[nb];
}

// ---------------- scatter edges into CSR slots ----------------
__global__ void k_scatter(const int* __restrict__ src, const int* __restrict__ dst,
                          int* __restrict__ cur, int* __restrict__ colx, int ne) {
    int e = blockIdx.x * blockDim.x + threadIdx.x;
    if (e < ne) {
        int pos = atomicAdd(&cur[dst[e]], 1);
        colx[pos] = src[e];
    }
}

// ---------------- W convert+transpose: Wt[n][k] = (fp16) W[k][n] ----------------
// launch <<<256, K>>>: blockIdx.x = n, threadIdx.x = k
__global__ void k_cvtW(const float* __restrict__ W, _Float16* __restrict__ Wt, int K) {
    int n = blockIdx.x;
    int k = threadIdx.x;
    Wt[(size_t)n * K + k] = (_Float16)W[(size_t)k * HID + n];
}

// ---------------- MFMA fp16 GEMM: C = epi(A[M,K] @ W[K,256]) ----------------
// block: 64 rows x 256 cols, 256 threads = 4 waves (2x2), BK=64.
// Wt is pre-transposed fp16 [256][K].
// EPI 0: A fp32; C fp16 = (acc + bias[c]) * scale[row0+r]   (per-type linear)
// EPI 1: A fp16; C fp32 = relu(acc + bias[c])               (final layer)
template <int K, int EPI>
__global__ __launch_bounds__(256) void k_mgemm(const void* __restrict__ Av,
                                               const _Float16* __restrict__ Wt,
                                               const float* __restrict__ bias,
                                               const float* __restrict__ scale,
                                               void* __restrict__ Cv,
                                               int M, int row0) {
    __shared__ _Float16 As[64][72];    // 64 rows x BK=64 (+8 pad: 2-way bank alias only)
    __shared__ _Float16 Bs[256][72];   // 256 cols x BK=64 (+8 pad)
    int t = threadIdx.x, lane = t & 63, wave = t >> 6;
    int wm = wave >> 1, wn = wave & 1;          // 2x2 wave grid
    int rbase = blockIdx.x * 64;
    int cl = lane & 15, kg = lane >> 4;         // fragment col / k-group

    f32x4 zero = {0.f, 0.f, 0.f, 0.f};
    f32x4 acc[2][8];
    #pragma unroll
    for (int i = 0; i < 2; i++)
        #pragma unroll
        for (int j = 0; j < 8; j++) acc[i][j] = zero;

    for (int k0 = 0; k0 < K; k0 += 64) {
        // ---- stage A tile (64 x 64), convert fp32->fp16 if EPI==0 ----
        {
            int r = t >> 2, seg = t & 3;           // each thread: 16 halves of one row
            int gr = rbase + r; if (gr >= M) gr = M - 1;
            if (EPI == 0) {
                const float* A = (const float*)Av;
                const float4* p = (const float4*)(A + (size_t)gr * K + k0 + seg * 16);
                float4 a = p[0], b = p[1], c = p[2], d = p[3];
                f16x8 h0 = {(_Float16)a.x, (_Float16)a.y, (_Float16)a.z, (_Float16)a.w,
                            (_Float16)b.x, (_Float16)b.y, (_Float16)b.z, (_Float16)b.w};
                f16x8 h1 = {(_Float16)c.x, (_Float16)c.y, (_Float16)c.z, (_Float16)c.w,
                            (_Float16)d.x, (_Float16)d.y, (_Float16)d.z, (_Float16)d.w};
                *(f16x8*)&As[r][seg * 16]     = h0;
                *(f16x8*)&As[r][seg * 16 + 8] = h1;
            } else {
                const _Float16* A = (const _Float16*)Av;
                const uint4* p = (const uint4*)(A + (size_t)gr * K + k0 + seg * 16);
                *(uint4*)&As[r][seg * 16]     = p[0];
                *(uint4*)&As[r][seg * 16 + 8] = p[1];
            }
        }
        // ---- stage B tile (256 cols x 64 k) from pre-transposed Wt ----
        {
            const uint4* p = (const uint4*)(Wt + (size_t)t * K + k0);
            #pragma unroll
            for (int j = 0; j < 8; j++) *(uint4*)&Bs[t][j * 8] = p[j];
        }
        __syncthreads();

        // ---- MFMA: wave computes 32 x 128 ----
        f16x8 af[2][2];
        #pragma unroll
        for (int mf = 0; mf < 2; mf++)
            #pragma unroll
            for (int c = 0; c < 2; c++)
                af[mf][c] = *(f16x8*)&As[wm * 32 + mf * 16 + cl][c * 32 + kg * 8];
        #pragma unroll
        for (int nf = 0; nf < 8; nf++) {
            int bn = wn * 128 + nf * 16 + cl;
            f16x8 bf0 = *(f16x8*)&Bs[bn][kg * 8];
            f16x8 bf1 = *(f16x8*)&Bs[bn][32 + kg * 8];
            acc[0][nf] = __builtin_amdgcn_mfma_f32_16x16x32_f16(af[0][0], bf0, acc[0][nf], 0, 0, 0);
            acc[0][nf] = __builtin_amdgcn_mfma_f32_16x16x32_f16(af[0][1], bf1, acc[0][nf], 0, 0, 0);
            acc[1][nf] = __builtin_amdgcn_mfma_f32_16x16x32_f16(af[1][0], bf0, acc[1][nf], 0, 0, 0);
            acc[1][nf] = __builtin_amdgcn_mfma_f32_16x16x32_f16(af[1][1], bf1, acc[1][nf], 0, 0, 0);
        }
        __syncthreads();
    }

    // ---- epilogue: C/D layout col=lane&15, row=(lane>>4)*4+reg ----
    #pragma unroll
    for (int mf = 0; mf < 2; mf++) {
        int lr = wm * 32 + mf * 16 + kg * 4;
        int g0 = rbase + lr;
        float s[4];
        if (EPI == 0) {
            #pragma unroll
            for (int r = 0; r < 4; r++) {
                int gr = g0 + r; if (gr >= M) gr = M - 1;
                s[r] = scale[row0 + gr];
            }
        }
        #pragma unroll
        for (int nf = 0; nf < 8; nf++) {
            int col = wn * 128 + nf * 16 + cl;
            float bb = bias[col];
            #pragma unroll
            for (int r = 0; r < 4; r++) {
                int gr = g0 + r;
                if (gr < M) {
                    float v = acc[mf][nf][r] + bb;
                    if (EPI == 0) {
                        ((_Float16*)Cv)[(size_t)(row0 + gr) * HID + col] = (_Float16)(v * s[r]);
                    } else {
                        ((float*)Cv)[(size_t)gr * HID + col] = fmaxf(v, 0.f);
                    }
                }
            }
        }
    }
}

// ---------------- pull-style SpMM over CSR (fp16 rows); 1 wave per dst node; 8x unrolled ----
// MODE 0: hout(fp16) = relu(acc*norm_in + bias) * norm_out  (layer-0 out, prescaled for layer 1)
// MODE 1: hout(fp16) = acc*norm_in                           (pre-GEMM agg for layer 1)
template <int MODE>
__global__ __launch_bounds__(256) void k_spmm(const __half* __restrict__ hin,
                                              const int* __restrict__ rp,
                                              const int* __restrict__ colx,
                                              const float* __restrict__ norm_in,
                                              const float* __restrict__ norm_out,
                                              const float* __restrict__ bias,
                                              __half* __restrict__ hout,
                                              int n) {
    int node = blockIdx.x * 4 + (threadIdx.x >> 6);
    if (node >= n) return;
    int lane = threadIdx.x & 63;
    int start = rp[node], end = rp[node + 1];
    const __half* hb = hin + lane * 4;   // each lane covers feature cols [lane*4, lane*4+4)

    float4 acc = make_float4(0.f, 0.f, 0.f, 0.f);
    float4 acc2 = make_float4(0.f, 0.f, 0.f, 0.f);
    int j = start;
    for (; j + 8 <= end; j += 8) {
        int s0 = colx[j + 0], s1 = colx[j + 1], s2 = colx[j + 2], s3 = colx[j + 3];
        int s4 = colx[j + 4], s5 = colx[j + 5], s6 = colx[j + 6], s7 = colx[j + 7];
        uint2 u0 = *(const uint2*)(hb + (size_t)s0 * HID);
        uint2 u1 = *(const uint2*)(hb + (size_t)s1 * HID);
        uint2 u2 = *(const uint2*)(hb + (size_t)s2 * HID);
        uint2 u3 = *(const uint2*)(hb + (size_t)s3 * HID);
        uint2 u4 = *(const uint2*)(hb + (size_t)s4 * HID);
        uint2 u5 = *(const uint2*)(hb + (size_t)s5 * HID);
        uint2 u6 = *(const uint2*)(hb + (size_t)s6 * HID);
        uint2 u7 = *(const uint2*)(hb + (size_t)s7 * HID);
        float4 v0 = u2_to_f4(u0), v1 = u2_to_f4(u1), v2 = u2_to_f4(u2), v3 = u2_to_f4(u3);
        float4 v4 = u2_to_f4(u4), v5 = u2_to_f4(u5), v6 = u2_to_f4(u6), v7 = u2_to_f4(u7);
        acc.x += v0.x + v1.x; acc.y += v0.y + v1.y; acc.z += v0.z + v1.z; acc.w += v0.w + v1.w;
        acc2.x += v2.x + v3.x; acc2.y += v2.y + v3.y; acc2.z += v2.z + v3.z; acc2.w += v2.w + v3.w;
        acc.x += v4.x + v5.x; acc.y += v4.y + v5.y; acc.z += v4.z + v5.z; acc.w += v4.w + v5.w;
        acc2.x += v6.x + v7.x; acc2.y += v6.y + v7.y; acc2.z += v6.z + v7.z; acc2.w += v6.w + v7.w;
    }
    for (; j < end; j++) {
        int s = colx[j];
        float4 v = u2_to_f4(*(const uint2*)(hb + (size_t)s * HID));
        acc.x += v.x; acc.y += v.y; acc.z += v.z; acc.w += v.w;
    }
    acc.x += acc2.x; acc.y += acc2.y; acc.z += acc2.z; acc.w += acc2.w;

    float ni = norm_in[node];
    uint2 st;
    if (MODE == 0) {
        float no = norm_out[node];
        float4 bb = *(const float4*)(bias + lane * 4);
        float o0 = fmaxf(acc.x * ni + bb.x, 0.f) * no;
        float o1 = fmaxf(acc.y * ni + bb.y, 0.f) * no;
        float o2 = fmaxf(acc.z * ni + bb.z, 0.f) * no;
        float o3 = fmaxf(acc.w * ni + bb.w, 0.f) * no;
        st.x = h2_as_u32(__floats2half2_rn(o0, o1));
        st.y = h2_as_u32(__floats2half2_rn(o2, o3));
    } else {
        st.x = h2_as_u32(__floats2half2_rn(acc.x * ni, acc.y * ni));
        st.y = h2_as_u32(__floats2half2_rn(acc.z * ni, acc.w * ni));
    }
    *(uint2*)(hout + (size_t)node * HID + lane * 4) = st;
}

extern "C" void kernel_launch(void* const* d_in, const int* in_sizes, int n_in,
                              void* d_out, int out_size, void* d_ws, size_t ws_size,
                              hipStream_t stream) {
    const float* x0      = (const float*)d_in[0];
    const float* x1      = (const float*)d_in[1];
    const float* x2      = (const float*)d_in[2];
    const float* W_fc0   = (const float*)d_in[3];
    const float* b_fc0   = (const float*)d_in[4];
    const float* W_fc1   = (const float*)d_in[5];
    const float* b_fc1   = (const float*)d_in[6];
    const float* W_fc2   = (const float*)d_in[7];
    const float* b_fc2   = (const float*)d_in[8];
    const float* bias_l0 = (const float*)d_in[9];
    const float* W_l1    = (const float*)d_in[10];
    const float* b_l1    = (const float*)d_in[11];
    const int*   src     = (const int*)d_in[12];
    const int*   dst     = (const int*)d_in[13];

    int n0 = in_sizes[0] / 256;
    int n1 = in_sizes[1] / 128;
    int n2 = in_sizes[2] / 512;
    int N  = n0 + n1 + n2;
    int NE = in_sizes[12];
    int nscan = (N + 1023) / 1024;

    // workspace layout (256B-aligned slices)
    char* w = (char*)d_ws;
    auto alloc = [&](size_t bytes) {
        char* p = w;
        w += (bytes + 255) & ~(size_t)255;
        return p;
    };
    int*      deg_out  = (int*)alloc((size_t)2 * N * sizeof(int)); // deg_out + deg_in contiguous
    int*      deg_in   = deg_out + N;
    float*    norm_out = (float*)alloc((size_t)N * sizeof(float));
    float*    norm_in  = (float*)alloc((size_t)N * sizeof(float));
    int*      row_ptr  = (int*)alloc((size_t)(N + 1) * sizeof(int));
    int*      cursor   = (int*)alloc((size_t)N * sizeof(int));
    int*      bsum     = (int*)alloc((size_t)(nscan + 1) * sizeof(int));
    int*      colx     = (int*)alloc((size_t)NE * sizeof(int));
    _Float16* Wt0      = (_Float16*)alloc((size_t)256 * 256 * 2);
    _Float16* Wt1      = (_Float16*)alloc((size_t)128 * 256 * 2);
    _Float16* Wt2      = (_Float16*)alloc((size_t)512 * 256 * 2);
    _Float16* WtL      = (_Float16*)alloc((size_t)256 * 256 * 2);
    __half*   h0h      = (__half*)alloc((size_t)N * HID * sizeof(__half));
    __half*   h1h      = (__half*)alloc((size_t)N * HID * sizeof(__half));
    __half*   aggh     = h0h;   // h0 is dead after layer-0 spmm; reuse for layer-1 agg

    // graph preprocessing
    hipMemsetAsync(deg_out, 0, (size_t)2 * N * sizeof(int), stream);
    k_deg<<<(NE + 255) / 256, 256, 0, stream>>>(src, dst, deg_out, deg_in, NE);
    k_norm<<<(N + 255) / 256, 256, 0, stream>>>(deg_out, deg_in, norm_out, norm_in, N);
    k_scan_local<<<nscan, 1024, 0, stream>>>(deg_in, row_ptr, bsum, N);
    k_scan_bsum<<<1, 64, 0, stream>>>(bsum, nscan);
    k_scan_add<<<nscan, 1024, 0, stream>>>(row_ptr, cursor, bsum, N, nscan);
    k_scatter<<<(NE + 255) / 256, 256, 0, stream>>>(src, dst, cursor, colx, NE);

    // weight convert+transpose to fp16
    k_cvtW<<<256, 256, 0, stream>>>(W_fc0, Wt0, 256);
    k_cvtW<<<256, 128, 0, stream>>>(W_fc1, Wt1, 128);
    k_cvtW<<<256, 512, 0, stream>>>(W_fc2, Wt2, 512);
    k_cvtW<<<256, 256, 0, stream>>>(W_l1,  WtL, 256);

    // per-type linear projections -> fp16 h0, prescaled by norm_out (MFMA)
    k_mgemm<256, 0><<<(n0 + 63) / 64, 256, 0, stream>>>(x0, Wt0, b_fc0, norm_out, h0h, n0, 0);
    k_mgemm<128, 0><<<(n1 + 63) / 64, 256, 0, stream>>>(x1, Wt1, b_fc1, norm_out, h0h, n1, n0);
    k_mgemm<512, 0><<<(n2 + 63) / 64, 256, 0, stream>>>(x2, Wt2, b_fc2, norm_out, h0h, n2, n0 + n1);

    // layer 0: agg + relu + prescale for layer 1 -> fp16 h1
    k_spmm<0><<<(N + 3) / 4, 256, 0, stream>>>(h0h, row_ptr, colx, norm_in, norm_out, bias_l0,
                                               h1h, N);
    // layer 1: agg (with norm_in) -> fp16 agg (aliases h0h)
    k_spmm<1><<<(N + 3) / 4, 256, 0, stream>>>(h1h, row_ptr, colx, norm_in, norm_out, nullptr,
                                               aggh, N);
    // final: relu(agg @ W_l1 + b_l1) -> fp32 d_out (MFMA)
    k_mgemm<256, 1><<<(N + 63) / 64, 256, 0, stream>>>(aggh, WtL, b_l1, nullptr, d_out, N, 0);
}